// Round 1
// baseline (795.352 us; speedup 1.0000x reference)
//
#include <hip/hip_runtime.h>

#define NROWS 131072
#define KDIM 512
#define NDIM 512

using short8  = __attribute__((ext_vector_type(8))) short;
using float4v = __attribute__((ext_vector_type(4))) float;
using uint4v  = __attribute__((ext_vector_type(4))) unsigned int;

// pack two fp32 -> bf16x2 (truncation; 1 v_perm per pair)
__device__ __forceinline__ unsigned pack_trunc(float a, float b) {
    unsigned ua = __builtin_bit_cast(unsigned, a);
    unsigned ub = __builtin_bit_cast(unsigned, b);
    return __builtin_amdgcn_perm(ub, ua, 0x07060302u);
}
// pack two fp32 -> bf16x2 (round-half-up on magnitude; off hot path)
__device__ __forceinline__ unsigned pack_round(float a, float b) {
    unsigned ua = __builtin_bit_cast(unsigned, a) + 0x8000u;
    unsigned ub = __builtin_bit_cast(unsigned, b) + 0x8000u;
    return __builtin_amdgcn_perm(ub, ua, 0x07060302u);
}

// async global->LDS, 16B per lane. LDS dest must be wave-uniform base + lane*16.
__device__ __forceinline__ void glds16(const void* g, void* l) {
    __builtin_amdgcn_global_load_lds(
        (__attribute__((address_space(1))) void*)g,
        (__attribute__((address_space(3))) void*)l, 16, 0, 0);
}

// Pass 1: W [8][512 in][512 out] fp32  ->  Wt [8][512 out][512 in] bf16
__global__ __launch_bounds__(256) void wconv_kernel(const float* __restrict__ w,
                                                    unsigned short* __restrict__ wt) {
    int b  = blockIdx.x;          // 512 blocks
    int ty = b >> 6;              // type 0..7
    int ot = (b >> 3) & 7;        // out-tile of 64
    int it = b & 7;               // in-tile of 64
    __shared__ float tile[64][65];
    const float* wp = w + ((size_t)ty << 18);
    int tid = threadIdx.x;
    int cf = tid & 15, ir0 = tid >> 4;
    #pragma unroll
    for (int j = 0; j < 4; ++j) {
        int ir = ir0 + 16 * j;
        float4v v = *(const float4v*)(wp + (size_t)(it * 64 + ir) * NDIM + ot * 64 + cf * 4);
        tile[ir][cf * 4 + 0] = v.x;
        tile[ir][cf * 4 + 1] = v.y;
        tile[ir][cf * 4 + 2] = v.z;
        tile[ir][cf * 4 + 3] = v.w;
    }
    __syncthreads();
    int oc = tid >> 2, iq = tid & 3;
    unsigned* op = (unsigned*)(wt + ((size_t)ty << 18) + (size_t)(ot * 64 + oc) * KDIM + it * 64 + iq * 16);
    #pragma unroll
    for (int j = 0; j < 8; ++j)
        op[j] = pack_round(tile[iq * 16 + 2 * j][oc], tile[iq * 16 + 2 * j + 1][oc]);
}

// Pass 2: out[128x128 tile] = bf16(x) @ Wt[t] + bias[t], per-row t, sorted.
// Double-buffered LDS, one barrier per 32-K chunk, 4 blocks/CU.
// Type handling: full unmasked GEMM per type in [t0,t1]; epilogue store
// predicated on tv[row]==tt (only ~28/4096 blocks span a boundary).
__global__ __launch_bounds__(256, 4)
void hetero_gemm_kernel(const float* __restrict__ x,
                        const int* __restrict__ tv,
                        const unsigned short* __restrict__ wt,
                        const float* __restrict__ bias,
                        float* __restrict__ out) {
    __shared__ uint4v ldsA[2][4 * 128];   // [buf][kgrp][row] 16B units (8 bf16, k-contig)
    __shared__ uint4v ldsB[2][4 * 128];   // [buf][kgrp][col]

    const int b = blockIdx.x;
    const int rowTile = ((b >> 5) << 3) | (b & 7);
    const int colTile = (b >> 3) & 3;
    const int row0 = rowTile << 7;
    const int col0 = colTile << 7;

    const int tid  = threadIdx.x;
    const int lane = tid & 63;
    const int wave = tid >> 6;
    const int wm   = (wave & 1) << 6;   // 0 / 64
    const int wn   = (wave >> 1) << 6;  // 0 / 64
    const int l15  = lane & 15;
    const int quad = lane >> 4;

    // A staging: thread -> (row ra, k-half khalf)  (16 fp32 each)
    const int ra    = tid >> 1;
    const int khalf = tid & 1;

    // B staging: thread -> (col nb, kgrp pair g2); lane-contiguous in LDS per wave
    const int nb = tid & 127;
    const int g2 = tid >> 7;

    const int t0 = tv[row0];
    const int t1 = tv[row0 + 127];

    const float* apBase = x + (size_t)(row0 + ra) * KDIM + khalf * 16;

    for (int tt = t0; tt <= t1; ++tt) {
        const unsigned short* wbase =
            wt + ((size_t)tt << 18) + (size_t)(col0 + nb) * KDIM + g2 * 8;

        float4v acc[4][4];
        float4v zero = {0.f, 0.f, 0.f, 0.f};
        #pragma unroll
        for (int i = 0; i < 4; ++i)
            #pragma unroll
            for (int j = 0; j < 4; ++j)
                acc[i][j] = zero;

        // ---- prologue: stage chunk 0 into buffer 0 ----
        float4v av[4];
        #pragma unroll
        for (int i = 0; i < 4; ++i) av[i] = *(const float4v*)(apBase + i * 4);
        glds16(wbase,      &ldsB[0][ g2      * 128 + nb]);
        glds16(wbase + 16, &ldsB[0][(g2 + 2) * 128 + nb]);
        {
            uint4v pa0, pa1;
            pa0.x = pack_trunc(av[0].x, av[0].y);
            pa0.y = pack_trunc(av[0].z, av[0].w);
            pa0.z = pack_trunc(av[1].x, av[1].y);
            pa0.w = pack_trunc(av[1].z, av[1].w);
            pa1.x = pack_trunc(av[2].x, av[2].y);
            pa1.y = pack_trunc(av[2].z, av[2].w);
            pa1.z = pack_trunc(av[3].x, av[3].y);
            pa1.w = pack_trunc(av[3].z, av[3].w);
            ldsA[0][(khalf * 2 + 0) * 128 + ra] = pa0;
            ldsA[0][(khalf * 2 + 1) * 128 + ra] = pa1;
        }
        __syncthreads();   // drains glds (vmcnt) + A writes (lgkmcnt)

        int cur = 0;
        for (int kc = 0; kc < KDIM; kc += 32) {
            // stage chunk kc+32 into buf^1: issue loads first (latency hides
            // under ds_read + MFMA below)
            if (kc + 32 < KDIM) {
                const float* ap2 = apBase + kc + 32;
                #pragma unroll
                for (int i = 0; i < 4; ++i) av[i] = *(const float4v*)(ap2 + i * 4);
                glds16(wbase + kc + 32,      &ldsB[cur ^ 1][ g2      * 128 + nb]);
                glds16(wbase + kc + 32 + 16, &ldsB[cur ^ 1][(g2 + 2) * 128 + nb]);
            }

            short8 af[4], bf[4];
            #pragma unroll
            for (int mi = 0; mi < 4; ++mi)
                af[mi] = *(const short8*)&ldsA[cur][quad * 128 + wm + mi * 16 + l15];
            #pragma unroll
            for (int ni = 0; ni < 4; ++ni)
                bf[ni] = *(const short8*)&ldsB[cur][quad * 128 + wn + ni * 16 + l15];

            #pragma unroll
            for (int mi = 0; mi < 4; ++mi)
                #pragma unroll
                for (int ni = 0; ni < 4; ++ni)
                    acc[mi][ni] = __builtin_amdgcn_mfma_f32_16x16x32_bf16(
                        af[mi], bf[ni], acc[mi][ni], 0, 0, 0);

            // pack A for next chunk after MFMA (global loads get max cover)
            if (kc + 32 < KDIM) {
                uint4v pa0, pa1;
                pa0.x = pack_trunc(av[0].x, av[0].y);
                pa0.y = pack_trunc(av[0].z, av[0].w);
                pa0.z = pack_trunc(av[1].x, av[1].y);
                pa0.w = pack_trunc(av[1].z, av[1].w);
                pa1.x = pack_trunc(av[2].x, av[2].y);
                pa1.y = pack_trunc(av[2].z, av[2].w);
                pa1.z = pack_trunc(av[3].x, av[3].y);
                pa1.w = pack_trunc(av[3].z, av[3].w);
                ldsA[cur ^ 1][(khalf * 2 + 0) * 128 + ra] = pa0;
                ldsA[cur ^ 1][(khalf * 2 + 1) * 128 + ra] = pa1;
            }
            __syncthreads();   // buf^1 ready; all reads of buf done
            cur ^= 1;
        }

        // epilogue: D row = quad*4+reg, col = lane&15 (m89-verified layout)
        float bcol[4];
        #pragma unroll
        for (int ni = 0; ni < 4; ++ni)
            bcol[ni] = bias[(size_t)tt * NDIM + col0 + wn + ni * 16 + l15];

        #pragma unroll
        for (int mi = 0; mi < 4; ++mi) {
            #pragma unroll
            for (int r = 0; r < 4; ++r) {
                const int grow = row0 + wm + mi * 16 + quad * 4 + r;
                if (tv[grow] == tt) {
                    float* orow = out + (size_t)grow * NDIM;
                    #pragma unroll
                    for (int ni = 0; ni < 4; ++ni) {
                        const int gcol = col0 + wn + ni * 16 + l15;
                        __builtin_nontemporal_store(acc[mi][ni][r] + bcol[ni], &orow[gcol]);
                    }
                }
            }
        }
    }
}

extern "C" void kernel_launch(void* const* d_in, const int* in_sizes, int n_in,
                              void* d_out, int out_size, void* d_ws, size_t ws_size,
                              hipStream_t stream) {
    const float* x    = (const float*)d_in[0];
    const int*   tv   = (const int*)d_in[1];
    const float* w    = (const float*)d_in[2];
    const float* bias = (const float*)d_in[3];
    float* out = (float*)d_out;
    unsigned short* wtr = (unsigned short*)d_ws;   // 8*512*512*2 = 4 MiB

    wconv_kernel<<<512, 256, 0, stream>>>(w, wtr);
    hetero_gemm_kernel<<<4096, 256, 0, stream>>>(x, tv, wtr, bias, out);
}

// Round 2
// 738.558 us; speedup vs baseline: 1.0769x; 1.0769x over previous
//
#include <hip/hip_runtime.h>

#define NROWS 131072
#define KDIM 512
#define NDIM 512

using short8  = __attribute__((ext_vector_type(8))) short;
using float4v = __attribute__((ext_vector_type(4))) float;
using uint4v  = __attribute__((ext_vector_type(4))) unsigned int;

// pack two fp32 -> bf16x2 (truncation; 1 v_perm per pair)
__device__ __forceinline__ unsigned pack_trunc(float a, float b) {
    unsigned ua = __builtin_bit_cast(unsigned, a);
    unsigned ub = __builtin_bit_cast(unsigned, b);
    return __builtin_amdgcn_perm(ub, ua, 0x07060302u);
}
// pack two fp32 -> bf16x2 (round-half-up on magnitude; off hot path)
__device__ __forceinline__ unsigned pack_round(float a, float b) {
    unsigned ua = __builtin_bit_cast(unsigned, a) + 0x8000u;
    unsigned ub = __builtin_bit_cast(unsigned, b) + 0x8000u;
    return __builtin_amdgcn_perm(ub, ua, 0x07060302u);
}

// async global->LDS, 16B per lane. LDS dest must be wave-uniform base + lane*16.
__device__ __forceinline__ void glds16(const void* g, void* l) {
    __builtin_amdgcn_global_load_lds(
        (__attribute__((address_space(1))) void*)g,
        (__attribute__((address_space(3))) void*)l, 16, 0, 0);
}

// Pass 1: W [8][512 in][512 out] fp32  ->  Wt [8][512 out][512 in] bf16
__global__ __launch_bounds__(256) void wconv_kernel(const float* __restrict__ w,
                                                    unsigned short* __restrict__ wt) {
    int b  = blockIdx.x;          // 512 blocks
    int ty = b >> 6;              // type 0..7
    int ot = (b >> 3) & 7;        // out-tile of 64
    int it = b & 7;               // in-tile of 64
    __shared__ float tile[64][65];
    const float* wp = w + ((size_t)ty << 18);
    int tid = threadIdx.x;
    int cf = tid & 15, ir0 = tid >> 4;
    #pragma unroll
    for (int j = 0; j < 4; ++j) {
        int ir = ir0 + 16 * j;
        float4v v = *(const float4v*)(wp + (size_t)(it * 64 + ir) * NDIM + ot * 64 + cf * 4);
        tile[ir][cf * 4 + 0] = v.x;
        tile[ir][cf * 4 + 1] = v.y;
        tile[ir][cf * 4 + 2] = v.z;
        tile[ir][cf * 4 + 3] = v.w;
    }
    __syncthreads();
    int oc = tid >> 2, iq = tid & 3;
    unsigned* op = (unsigned*)(wt + ((size_t)ty << 18) + (size_t)(ot * 64 + oc) * KDIM + it * 64 + iq * 16);
    #pragma unroll
    for (int j = 0; j < 8; ++j)
        op[j] = pack_round(tile[iq * 16 + 2 * j][oc], tile[iq * 16 + 2 * j + 1][oc]);
}

// Pass 2: out[128x128 tile] = bf16(x) @ Wt[t] + bias[t], per-row t, sorted.
// Double-buffered LDS, one barrier per 32-K chunk.
// __launch_bounds__(256,3): 170-reg budget -> no spill (round-1's (256,4)
// squeezed to 128 and spilled ~1GB of scratch traffic), 3 blocks/CU.
// Type handling: full unmasked GEMM per type in [t0,t1]; epilogue store
// predicated on tv[row]==tt (only ~28/4096 blocks span a boundary).
__global__ __launch_bounds__(256, 3)
void hetero_gemm_kernel(const float* __restrict__ x,
                        const int* __restrict__ tv,
                        const unsigned short* __restrict__ wt,
                        const float* __restrict__ bias,
                        float* __restrict__ out) {
    __shared__ uint4v ldsA[2][4 * 128];   // [buf][kgrp][row] 16B units (8 bf16, k-contig)
    __shared__ uint4v ldsB[2][4 * 128];   // [buf][kgrp][col]

    const int b = blockIdx.x;
    const int rowTile = ((b >> 5) << 3) | (b & 7);
    const int colTile = (b >> 3) & 3;
    const int row0 = rowTile << 7;
    const int col0 = colTile << 7;

    const int tid  = threadIdx.x;
    const int lane = tid & 63;
    const int wave = tid >> 6;
    const int wm   = (wave & 1) << 6;   // 0 / 64
    const int wn   = (wave >> 1) << 6;  // 0 / 64
    const int l15  = lane & 15;
    const int quad = lane >> 4;

    // A staging: thread -> (row ra, k-half khalf)  (16 fp32 each)
    const int ra    = tid >> 1;
    const int khalf = tid & 1;

    // B staging: thread -> (col nb, kgrp pair g2); lane-contiguous in LDS per wave
    const int nb = tid & 127;
    const int g2 = tid >> 7;

    const int t0 = tv[row0];
    const int t1 = tv[row0 + 127];

    const float* apBase = x + (size_t)(row0 + ra) * KDIM + khalf * 16;

    for (int tt = t0; tt <= t1; ++tt) {
        const unsigned short* wbase =
            wt + ((size_t)tt << 18) + (size_t)(col0 + nb) * KDIM + g2 * 8;

        float4v acc[4][4];
        float4v zero = {0.f, 0.f, 0.f, 0.f};
        #pragma unroll
        for (int i = 0; i < 4; ++i)
            #pragma unroll
            for (int j = 0; j < 4; ++j)
                acc[i][j] = zero;

        // ---- prologue: stage chunk 0 into buffer 0 ----
        float4v av[4];
        #pragma unroll
        for (int i = 0; i < 4; ++i) av[i] = *(const float4v*)(apBase + i * 4);
        glds16(wbase,      &ldsB[0][ g2      * 128 + nb]);
        glds16(wbase + 16, &ldsB[0][(g2 + 2) * 128 + nb]);
        {
            uint4v pa0, pa1;
            pa0.x = pack_trunc(av[0].x, av[0].y);
            pa0.y = pack_trunc(av[0].z, av[0].w);
            pa0.z = pack_trunc(av[1].x, av[1].y);
            pa0.w = pack_trunc(av[1].z, av[1].w);
            pa1.x = pack_trunc(av[2].x, av[2].y);
            pa1.y = pack_trunc(av[2].z, av[2].w);
            pa1.z = pack_trunc(av[3].x, av[3].y);
            pa1.w = pack_trunc(av[3].z, av[3].w);
            ldsA[0][(khalf * 2 + 0) * 128 + ra] = pa0;
            ldsA[0][(khalf * 2 + 1) * 128 + ra] = pa1;
        }
        __syncthreads();   // drains glds (vmcnt) + A writes (lgkmcnt)

        int cur = 0;
        for (int kc = 0; kc < KDIM; kc += 32) {
            // stage chunk kc+32 into buf^1: issue loads first (latency hides
            // under ds_read + MFMA below)
            if (kc + 32 < KDIM) {
                const float* ap2 = apBase + kc + 32;
                #pragma unroll
                for (int i = 0; i < 4; ++i) av[i] = *(const float4v*)(ap2 + i * 4);
                glds16(wbase + kc + 32,      &ldsB[cur ^ 1][ g2      * 128 + nb]);
                glds16(wbase + kc + 32 + 16, &ldsB[cur ^ 1][(g2 + 2) * 128 + nb]);
            }

            short8 af[4], bf[4];
            #pragma unroll
            for (int mi = 0; mi < 4; ++mi)
                af[mi] = *(const short8*)&ldsA[cur][quad * 128 + wm + mi * 16 + l15];
            #pragma unroll
            for (int ni = 0; ni < 4; ++ni)
                bf[ni] = *(const short8*)&ldsB[cur][quad * 128 + wn + ni * 16 + l15];

            #pragma unroll
            for (int mi = 0; mi < 4; ++mi)
                #pragma unroll
                for (int ni = 0; ni < 4; ++ni)
                    acc[mi][ni] = __builtin_amdgcn_mfma_f32_16x16x32_bf16(
                        af[mi], bf[ni], acc[mi][ni], 0, 0, 0);

            // pack A for next chunk after MFMA (global loads get max cover)
            if (kc + 32 < KDIM) {
                uint4v pa0, pa1;
                pa0.x = pack_trunc(av[0].x, av[0].y);
                pa0.y = pack_trunc(av[0].z, av[0].w);
                pa0.z = pack_trunc(av[1].x, av[1].y);
                pa0.w = pack_trunc(av[1].z, av[1].w);
                pa1.x = pack_trunc(av[2].x, av[2].y);
                pa1.y = pack_trunc(av[2].z, av[2].w);
                pa1.z = pack_trunc(av[3].x, av[3].y);
                pa1.w = pack_trunc(av[3].z, av[3].w);
                ldsA[cur ^ 1][(khalf * 2 + 0) * 128 + ra] = pa0;
                ldsA[cur ^ 1][(khalf * 2 + 1) * 128 + ra] = pa1;
            }
            __syncthreads();   // buf^1 ready; all reads of buf done
            cur ^= 1;
        }

        // epilogue: D row = quad*4+reg, col = lane&15 (m89-verified layout)
        float bcol[4];
        #pragma unroll
        for (int ni = 0; ni < 4; ++ni)
            bcol[ni] = bias[(size_t)tt * NDIM + col0 + wn + ni * 16 + l15];

        #pragma unroll
        for (int mi = 0; mi < 4; ++mi) {
            #pragma unroll
            for (int r = 0; r < 4; ++r) {
                const int grow = row0 + wm + mi * 16 + quad * 4 + r;
                if (tv[grow] == tt) {
                    float* orow = out + (size_t)grow * NDIM;
                    #pragma unroll
                    for (int ni = 0; ni < 4; ++ni) {
                        const int gcol = col0 + wn + ni * 16 + l15;
                        orow[gcol] = acc[mi][ni][r] + bcol[ni];
                    }
                }
            }
        }
    }
}

extern "C" void kernel_launch(void* const* d_in, const int* in_sizes, int n_in,
                              void* d_out, int out_size, void* d_ws, size_t ws_size,
                              hipStream_t stream) {
    const float* x    = (const float*)d_in[0];
    const int*   tv   = (const int*)d_in[1];
    const float* w    = (const float*)d_in[2];
    const float* bias = (const float*)d_in[3];
    float* out = (float*)d_out;
    unsigned short* wtr = (unsigned short*)d_ws;   // 8*512*512*2 = 4 MiB

    wconv_kernel<<<512, 256, 0, stream>>>(w, wtr);
    hetero_gemm_kernel<<<4096, 256, 0, stream>>>(x, tv, wtr, bias, out);
}

// Round 3
// 671.123 us; speedup vs baseline: 1.1851x; 1.1005x over previous
//
#include <hip/hip_runtime.h>

#define NROWS 131072
#define KDIM 512
#define NDIM 512

using short8  = __attribute__((ext_vector_type(8))) short;
using float4v = __attribute__((ext_vector_type(4))) float;
using uint4v  = __attribute__((ext_vector_type(4))) unsigned int;

// pack two fp32 -> bf16x2 (truncation; 1 v_perm per pair)
__device__ __forceinline__ unsigned pack_trunc(float a, float b) {
    unsigned ua = __builtin_bit_cast(unsigned, a);
    unsigned ub = __builtin_bit_cast(unsigned, b);
    return __builtin_amdgcn_perm(ub, ua, 0x07060302u);
}
// pack two fp32 -> bf16x2 (round-half-up on magnitude; off hot path)
__device__ __forceinline__ unsigned pack_round(float a, float b) {
    unsigned ua = __builtin_bit_cast(unsigned, a) + 0x8000u;
    unsigned ub = __builtin_bit_cast(unsigned, b) + 0x8000u;
    return __builtin_amdgcn_perm(ub, ua, 0x07060302u);
}

// async global->LDS, 16B per lane. LDS dest must be wave-uniform base + lane*16.
__device__ __forceinline__ void glds16(const void* g, void* l) {
    __builtin_amdgcn_global_load_lds(
        (__attribute__((address_space(1))) void*)g,
        (__attribute__((address_space(3))) void*)l, 16, 0, 0);
}

// Pass 1a: W [8][512 in][512 out] fp32  ->  Wt [8][512 out][512 in] bf16
__global__ __launch_bounds__(256) void wconv_kernel(const float* __restrict__ w,
                                                    unsigned short* __restrict__ wt) {
    int b  = blockIdx.x;          // 512 blocks
    int ty = b >> 6;              // type 0..7
    int ot = (b >> 3) & 7;        // out-tile of 64
    int it = b & 7;               // in-tile of 64
    __shared__ float tile[64][65];
    const float* wp = w + ((size_t)ty << 18);
    int tid = threadIdx.x;
    int cf = tid & 15, ir0 = tid >> 4;
    #pragma unroll
    for (int j = 0; j < 4; ++j) {
        int ir = ir0 + 16 * j;
        float4v v = *(const float4v*)(wp + (size_t)(it * 64 + ir) * NDIM + ot * 64 + cf * 4);
        tile[ir][cf * 4 + 0] = v.x;
        tile[ir][cf * 4 + 1] = v.y;
        tile[ir][cf * 4 + 2] = v.z;
        tile[ir][cf * 4 + 3] = v.w;
    }
    __syncthreads();
    int oc = tid >> 2, iq = tid & 3;
    unsigned* op = (unsigned*)(wt + ((size_t)ty << 18) + (size_t)(ot * 64 + oc) * KDIM + it * 64 + iq * 16);
    #pragma unroll
    for (int j = 0; j < 8; ++j)
        op[j] = pack_round(tile[iq * 16 + 2 * j][oc], tile[iq * 16 + 2 * j + 1][oc]);
}

// Pass 1b: x [131072][512] fp32 -> xb bf16 (rounded). Streaming, ~400 MB total.
// NT loads: x-fp32 is never re-read; don't evict the xb we're writing from L3.
__global__ __launch_bounds__(256) void xconv_kernel(const float* __restrict__ x,
                                                    unsigned short* __restrict__ xb) {
    const size_t total = (size_t)NROWS * KDIM / 8;   // 8 floats per thread-iter
    size_t i = (size_t)blockIdx.x * 256 + threadIdx.x;
    const size_t stride = (size_t)gridDim.x * 256;
    const float4v* xv = (const float4v*)x;
    uint4v* ov = (uint4v*)xb;
    for (; i < total; i += stride) {
        float4v a = __builtin_nontemporal_load(&xv[2 * i]);
        float4v c = __builtin_nontemporal_load(&xv[2 * i + 1]);
        uint4v o;
        o.x = pack_round(a.x, a.y);
        o.y = pack_round(a.z, a.w);
        o.z = pack_round(c.x, c.y);
        o.w = pack_round(c.z, c.w);
        ov[i] = o;
    }
}

// Pass 2 (fast path): out[128x128] = xb @ Wt[t] + bias[t].
// Both A and B staged via global_load_lds width=16: no staging registers,
// no pack VALU in the hot loop (rounds 1-2 showed the in-loop A-pack's
// register working set spills at any budget < 256). Double-buffered LDS,
// one barrier per 32-K chunk.
// Type handling: full unmasked GEMM per type in [t0,t1]; epilogue store
// predicated on tv[row]==tt (only ~28/4096 blocks span a boundary).
__global__ __launch_bounds__(256, 3)
void hetero_gemm_pre(const unsigned short* __restrict__ xb,
                     const int* __restrict__ tv,
                     const unsigned short* __restrict__ wt,
                     const float* __restrict__ bias,
                     float* __restrict__ out) {
    __shared__ uint4v ldsA[2][4 * 128];   // [buf][kgrp][row] 16B units (8 bf16, k-contig)
    __shared__ uint4v ldsB[2][4 * 128];   // [buf][kgrp][col]

    const int b = blockIdx.x;
    const int rowTile = ((b >> 5) << 3) | (b & 7);
    const int colTile = (b >> 3) & 3;
    const int row0 = rowTile << 7;
    const int col0 = colTile << 7;

    const int tid  = threadIdx.x;
    const int lane = tid & 63;
    const int wave = tid >> 6;
    const int wm   = (wave & 1) << 6;   // 0 / 64
    const int wn   = (wave >> 1) << 6;  // 0 / 64
    const int l15  = lane & 15;
    const int quad = lane >> 4;

    // staging: thread -> (i128 = row/col, g2 = kgrp base); each thread issues
    // units g2*128+i128 and (g2+2)*128+i128 -> per-wave LDS dests are
    // uniform-base + lane*16 (glds requirement), verified layout from r1/r2 B-path.
    const int i128 = tid & 127;
    const int g2   = tid >> 7;

    const int t0 = tv[row0];
    const int t1 = tv[row0 + 127];

    const unsigned short* abase = xb + (size_t)(row0 + i128) * KDIM + g2 * 8;

    for (int tt = t0; tt <= t1; ++tt) {
        const unsigned short* wbase =
            wt + ((size_t)tt << 18) + (size_t)(col0 + i128) * KDIM + g2 * 8;

        float4v acc[4][4];
        float4v zero = {0.f, 0.f, 0.f, 0.f};
        #pragma unroll
        for (int i = 0; i < 4; ++i)
            #pragma unroll
            for (int j = 0; j < 4; ++j)
                acc[i][j] = zero;

        // prologue: stage chunk 0 -> buf 0
        glds16(abase,      &ldsA[0][ g2      * 128 + i128]);
        glds16(abase + 16, &ldsA[0][(g2 + 2) * 128 + i128]);
        glds16(wbase,      &ldsB[0][ g2      * 128 + i128]);
        glds16(wbase + 16, &ldsB[0][(g2 + 2) * 128 + i128]);
        __syncthreads();   // vmcnt(0) drain: buf0 ready

        int cur = 0;
        for (int kc = 0; kc < KDIM; kc += 32) {
            // issue next chunk's staging first: latency hides under ds_read+MFMA
            if (kc + 32 < KDIM) {
                glds16(abase + kc + 32,      &ldsA[cur ^ 1][ g2      * 128 + i128]);
                glds16(abase + kc + 48,      &ldsA[cur ^ 1][(g2 + 2) * 128 + i128]);
                glds16(wbase + kc + 32,      &ldsB[cur ^ 1][ g2      * 128 + i128]);
                glds16(wbase + kc + 48,      &ldsB[cur ^ 1][(g2 + 2) * 128 + i128]);
            }

            short8 af[4], bf[4];
            #pragma unroll
            for (int mi = 0; mi < 4; ++mi)
                af[mi] = *(const short8*)&ldsA[cur][quad * 128 + wm + mi * 16 + l15];
            #pragma unroll
            for (int ni = 0; ni < 4; ++ni)
                bf[ni] = *(const short8*)&ldsB[cur][quad * 128 + wn + ni * 16 + l15];

            #pragma unroll
            for (int mi = 0; mi < 4; ++mi)
                #pragma unroll
                for (int ni = 0; ni < 4; ++ni)
                    acc[mi][ni] = __builtin_amdgcn_mfma_f32_16x16x32_bf16(
                        af[mi], bf[ni], acc[mi][ni], 0, 0, 0);

            __syncthreads();   // drains next-chunk glds; buf^1 ready
            cur ^= 1;
        }

        // epilogue: D row = quad*4+reg, col = lane&15 (m89-verified layout)
        float bcol[4];
        #pragma unroll
        for (int ni = 0; ni < 4; ++ni)
            bcol[ni] = bias[(size_t)tt * NDIM + col0 + wn + ni * 16 + l15];

        #pragma unroll
        for (int mi = 0; mi < 4; ++mi) {
            #pragma unroll
            for (int r = 0; r < 4; ++r) {
                const int grow = row0 + wm + mi * 16 + quad * 4 + r;
                if (tv[grow] == tt) {
                    float* orow = out + (size_t)grow * NDIM;
                    #pragma unroll
                    for (int ni = 0; ni < 4; ++ni) {
                        const int gcol = col0 + wn + ni * 16 + l15;
                        // NT: out is write-once; keep xb resident in L3
                        __builtin_nontemporal_store(acc[mi][ni][r] + bcol[ni], &orow[gcol]);
                    }
                }
            }
        }
    }
}

// Fallback (workspace too small for xb): round-0 proven kernel, 241 us, no spill.
__global__ __launch_bounds__(256, 2)
void hetero_gemm_fallback(const float* __restrict__ x,
                          const int* __restrict__ tv,
                          const unsigned short* __restrict__ wt,
                          const float* __restrict__ bias,
                          float* __restrict__ out) {
    __shared__ uint4v ldsA[4 * 128];
    __shared__ uint4v ldsB[4 * 128];

    const int b = blockIdx.x;
    const int rowTile = ((b >> 5) << 3) | (b & 7);
    const int colTile = (b >> 3) & 3;
    const int row0 = rowTile << 7;
    const int col0 = colTile << 7;

    const int tid  = threadIdx.x;
    const int lane = tid & 63;
    const int wave = tid >> 6;
    const int wm   = (wave & 1) << 6;
    const int wn   = (wave >> 1) << 6;
    const int l15  = lane & 15;
    const int quad = lane >> 4;

    const int ra = tid >> 1;
    const int khalf = tid & 1;
    const int rtypeA = tv[row0 + ra];

    const int nb = tid & 127;
    const int g2 = tid >> 7;

    const int t0 = tv[row0];
    const int t1 = tv[row0 + 127];

    float4v acc[4][4];
    float4v zero = {0.f, 0.f, 0.f, 0.f};
    #pragma unroll
    for (int i = 0; i < 4; ++i)
        #pragma unroll
        for (int j = 0; j < 4; ++j)
            acc[i][j] = zero;

    for (int tt = t0; tt <= t1; ++tt) {
        const unsigned maskA = (rtypeA == tt) ? 0xFFFFFFFFu : 0u;
        const float* ap = x + (size_t)(row0 + ra) * KDIM + khalf * 16;
        const unsigned short* wb = wt + ((size_t)tt << 18) + (size_t)(col0 + nb) * KDIM;

        float4v av[4];
        uint4v  bv[2];
        #pragma unroll
        for (int i = 0; i < 4; ++i) av[i] = *(const float4v*)(ap + i * 4);
        bv[0] = *(const uint4v*)(wb + g2 * 8);
        bv[1] = *(const uint4v*)(wb + (g2 + 2) * 8);

        for (int kc = 0; kc < KDIM; kc += 32) {
            __syncthreads();
            uint4v pa0, pa1;
            pa0.x = pack_trunc(av[0].x, av[0].y) & maskA;
            pa0.y = pack_trunc(av[0].z, av[0].w) & maskA;
            pa0.z = pack_trunc(av[1].x, av[1].y) & maskA;
            pa0.w = pack_trunc(av[1].z, av[1].w) & maskA;
            pa1.x = pack_trunc(av[2].x, av[2].y) & maskA;
            pa1.y = pack_trunc(av[2].z, av[2].w) & maskA;
            pa1.z = pack_trunc(av[3].x, av[3].y) & maskA;
            pa1.w = pack_trunc(av[3].z, av[3].w) & maskA;
            ldsA[(khalf * 2 + 0) * 128 + ra] = pa0;
            ldsA[(khalf * 2 + 1) * 128 + ra] = pa1;
            ldsB[(g2    ) * 128 + nb] = bv[0];
            ldsB[(g2 + 2) * 128 + nb] = bv[1];
            __syncthreads();

            if (kc + 32 < KDIM) {
                const float* ap2 = ap + kc + 32;
                #pragma unroll
                for (int i = 0; i < 4; ++i) av[i] = *(const float4v*)(ap2 + i * 4);
                const unsigned short* wb2 = wb + kc + 32;
                bv[0] = *(const uint4v*)(wb2 + g2 * 8);
                bv[1] = *(const uint4v*)(wb2 + (g2 + 2) * 8);
            }

            short8 af[4], bf[4];
            #pragma unroll
            for (int mi = 0; mi < 4; ++mi)
                af[mi] = *(const short8*)&ldsA[quad * 128 + wm + mi * 16 + l15];
            #pragma unroll
            for (int ni = 0; ni < 4; ++ni)
                bf[ni] = *(const short8*)&ldsB[quad * 128 + wn + ni * 16 + l15];
            #pragma unroll
            for (int mi = 0; mi < 4; ++mi)
                #pragma unroll
                for (int ni = 0; ni < 4; ++ni)
                    acc[mi][ni] = __builtin_amdgcn_mfma_f32_16x16x32_bf16(
                        af[mi], bf[ni], acc[mi][ni], 0, 0, 0);
        }
    }

    #pragma unroll
    for (int mi = 0; mi < 4; ++mi) {
        #pragma unroll
        for (int r = 0; r < 4; ++r) {
            const int grow = row0 + wm + mi * 16 + quad * 4 + r;
            const int rt = tv[grow];
            const float* brow = bias + (size_t)rt * NDIM;
            float* orow = out + (size_t)grow * NDIM;
            #pragma unroll
            for (int ni = 0; ni < 4; ++ni) {
                const int gcol = col0 + wn + ni * 16 + l15;
                orow[gcol] = acc[mi][ni][r] + brow[gcol];
            }
        }
    }
}

extern "C" void kernel_launch(void* const* d_in, const int* in_sizes, int n_in,
                              void* d_out, int out_size, void* d_ws, size_t ws_size,
                              hipStream_t stream) {
    const float* x    = (const float*)d_in[0];
    const int*   tv   = (const int*)d_in[1];
    const float* w    = (const float*)d_in[2];
    const float* bias = (const float*)d_in[3];
    float* out = (float*)d_out;

    unsigned short* wtr = (unsigned short*)d_ws;                 // 4 MiB
    const size_t WTN  = (size_t)8 * 512 * 512;                   // wtr elems
    const size_t NEED = WTN * 2 + (size_t)NROWS * KDIM * 2;      // 132 MiB

    wconv_kernel<<<512, 256, 0, stream>>>(w, wtr);
    if (ws_size >= NEED) {
        unsigned short* xb = wtr + WTN;                          // 128 MiB
        xconv_kernel<<<2048, 256, 0, stream>>>(x, xb);
        hetero_gemm_pre<<<4096, 256, 0, stream>>>(xb, tv, wtr, bias, out);
    } else {
        hetero_gemm_fallback<<<4096, 256, 0, stream>>>(x, tv, wtr, bias, out);
    }
}

// Round 4
// 604.689 us; speedup vs baseline: 1.3153x; 1.1099x over previous
//
#include <hip/hip_runtime.h>

#define NROWS 131072
#define KDIM 512
#define NDIM 512

using short8  = __attribute__((ext_vector_type(8))) short;
using float4v = __attribute__((ext_vector_type(4))) float;
using uint4v  = __attribute__((ext_vector_type(4))) unsigned int;

// pack two fp32 -> bf16x2 (truncation; 1 v_perm per pair)
__device__ __forceinline__ unsigned pack_trunc(float a, float b) {
    unsigned ua = __builtin_bit_cast(unsigned, a);
    unsigned ub = __builtin_bit_cast(unsigned, b);
    return __builtin_amdgcn_perm(ub, ua, 0x07060302u);
}
// pack two fp32 -> bf16x2 (round-half-up on magnitude; off hot path)
__device__ __forceinline__ unsigned pack_round(float a, float b) {
    unsigned ua = __builtin_bit_cast(unsigned, a) + 0x8000u;
    unsigned ub = __builtin_bit_cast(unsigned, b) + 0x8000u;
    return __builtin_amdgcn_perm(ub, ua, 0x07060302u);
}

// async global->LDS, 16B per lane. LDS dest must be wave-uniform base + lane*16.
__device__ __forceinline__ void glds16(const void* g, void* l) {
    __builtin_amdgcn_global_load_lds(
        (__attribute__((address_space(1))) void*)g,
        (__attribute__((address_space(3))) void*)l, 16, 0, 0);
}

// Pass 1 (merged): blocks [0,512): W fp32 -> Wt bf16 transposed
//                  blocks [512,2560): x fp32 -> xb bf16 streaming
__global__ __launch_bounds__(256) void prep_kernel(const float* __restrict__ w,
                                                   unsigned short* __restrict__ wt,
                                                   const float* __restrict__ x,
                                                   unsigned short* __restrict__ xb) {
    __shared__ float tile[64][65];
    if (blockIdx.x < 512) {
        int b  = blockIdx.x;
        int ty = b >> 6;              // type 0..7
        int ot = (b >> 3) & 7;        // out-tile of 64
        int it = b & 7;               // in-tile of 64
        const float* wp = w + ((size_t)ty << 18);
        int tid = threadIdx.x;
        int cf = tid & 15, ir0 = tid >> 4;
        #pragma unroll
        for (int j = 0; j < 4; ++j) {
            int ir = ir0 + 16 * j;
            float4v v = *(const float4v*)(wp + (size_t)(it * 64 + ir) * NDIM + ot * 64 + cf * 4);
            tile[ir][cf * 4 + 0] = v.x;
            tile[ir][cf * 4 + 1] = v.y;
            tile[ir][cf * 4 + 2] = v.z;
            tile[ir][cf * 4 + 3] = v.w;
        }
        __syncthreads();
        int oc = tid >> 2, iq = tid & 3;
        unsigned* op = (unsigned*)(wt + ((size_t)ty << 18) + (size_t)(ot * 64 + oc) * KDIM + it * 64 + iq * 16);
        #pragma unroll
        for (int j = 0; j < 8; ++j)
            op[j] = pack_round(tile[iq * 16 + 2 * j][oc], tile[iq * 16 + 2 * j + 1][oc]);
    } else {
        const size_t total = (size_t)NROWS * KDIM / 8;   // 8 floats per thread-iter
        size_t i = (size_t)(blockIdx.x - 512) * 256 + threadIdx.x;
        const size_t stride = (size_t)2048 * 256;
        const float4v* xv = (const float4v*)x;
        uint4v* ov = (uint4v*)xb;
        for (; i < total; i += stride) {
            float4v a = __builtin_nontemporal_load(&xv[2 * i]);
            float4v c = __builtin_nontemporal_load(&xv[2 * i + 1]);
            uint4v o;
            o.x = pack_round(a.x, a.y);
            o.y = pack_round(a.z, a.w);
            o.z = pack_round(c.x, c.y);
            o.w = pack_round(c.z, c.w);
            ov[i] = o;   // plain store: keep xb L3-resident for the GEMM
        }
    }
}

// Pass 2: out[128x128] = xb @ Wt[t] + bias[t].
// 4-buffer LDS ring, prefetch depth 3, counted vmcnt (8 loads in flight
// across every barrier; T3+T4 from m218), ONE raw s_barrier per 32-K chunk.
// Safety: buffer staged at iter k == buffer read at iter k-1; every wave's
// iter-(k-1) ds_reads complete before its iter-k barrier entry (auto lgkmcnt
// before MFMA), so post-barrier glds cannot race them.
// Type handling: full unmasked GEMM per type in [t0,t1]; epilogue store
// predicated on tv[row]==tt (only ~28/4096 blocks span a boundary).
__global__ __launch_bounds__(256, 2)
void hetero_gemm_pre(const unsigned short* __restrict__ xb,
                     const int* __restrict__ tv,
                     const unsigned short* __restrict__ wt,
                     const float* __restrict__ bias,
                     float* __restrict__ out) {
    __shared__ uint4v ldsA[4][4 * 128];   // [buf][kgrp][row] 16B units (8 bf16, k-contig)
    __shared__ uint4v ldsB[4][4 * 128];   // [buf][kgrp][col]    total 64 KiB

    const int b = blockIdx.x;
    const int rowTile = ((b >> 5) << 3) | (b & 7);
    const int colTile = (b >> 3) & 3;
    const int row0 = rowTile << 7;
    const int col0 = colTile << 7;

    const int tid  = threadIdx.x;
    const int lane = tid & 63;
    const int wave = tid >> 6;
    const int wm   = (wave & 1) << 6;   // 0 / 64
    const int wn   = (wave >> 1) << 6;  // 0 / 64
    const int l15  = lane & 15;
    const int quad = lane >> 4;

    // staging: thread -> (i128 = row/col, g2 = kgrp base); per-wave LDS dests
    // are uniform-base + lane*16 (glds requirement).
    const int i128 = tid & 127;
    const int g2   = tid >> 7;

    const int t0 = tv[row0];
    const int t1 = tv[row0 + 127];

    const unsigned short* abase = xb + (size_t)(row0 + i128) * KDIM + g2 * 8;

    for (int tt = t0; tt <= t1; ++tt) {
        const unsigned short* wbase =
            wt + ((size_t)tt << 18) + (size_t)(col0 + i128) * KDIM + g2 * 8;

        float4v acc[4][4];
        float4v zero = {0.f, 0.f, 0.f, 0.f};
        #pragma unroll
        for (int i = 0; i < 4; ++i)
            #pragma unroll
            for (int j = 0; j < 4; ++j)
                acc[i][j] = zero;

#define STAGE(c, bufi)                                                       \
    do {                                                                     \
        glds16(abase + (c) * 32,      &ldsA[bufi][ g2      * 128 + i128]);   \
        glds16(abase + (c) * 32 + 16, &ldsA[bufi][(g2 + 2) * 128 + i128]);   \
        glds16(wbase + (c) * 32,      &ldsB[bufi][ g2      * 128 + i128]);   \
        glds16(wbase + (c) * 32 + 16, &ldsB[bufi][(g2 + 2) * 128 + i128]);   \
    } while (0)

        // prologue: 3 chunks in flight (12 glds/thread)
        STAGE(0, 0);
        STAGE(1, 1);
        STAGE(2, 2);

        #pragma unroll
        for (int k = 0; k < 16; ++k) {
            // wait for chunk k's 4 glds only; keep later chunks in flight
            if (k < 14)       asm volatile("s_waitcnt vmcnt(8)" ::: "memory");
            else if (k == 14) asm volatile("s_waitcnt vmcnt(4)" ::: "memory");
            else              asm volatile("s_waitcnt vmcnt(0)" ::: "memory");
            __builtin_amdgcn_s_barrier();

            const int cur = k & 3;

            // issue next prefetch first: max flight time under ds_read+MFMA
            if (k + 3 < 16) STAGE(k + 3, (k + 3) & 3);

            short8 af[4], bf[4];
            #pragma unroll
            for (int mi = 0; mi < 4; ++mi)
                af[mi] = *(const short8*)&ldsA[cur][quad * 128 + wm + mi * 16 + l15];
            #pragma unroll
            for (int ni = 0; ni < 4; ++ni)
                bf[ni] = *(const short8*)&ldsB[cur][quad * 128 + wn + ni * 16 + l15];

            #pragma unroll
            for (int mi = 0; mi < 4; ++mi)
                #pragma unroll
                for (int ni = 0; ni < 4; ++ni)
                    acc[mi][ni] = __builtin_amdgcn_mfma_f32_16x16x32_bf16(
                        af[mi], bf[ni], acc[mi][ni], 0, 0, 0);
        }
#undef STAGE

        // epilogue: D row = quad*4+reg, col = lane&15 (m89-verified layout)
        // plain stores: NT caused 2x write amplification (r3: WRITE 530MB vs 268)
        float bcol[4];
        #pragma unroll
        for (int ni = 0; ni < 4; ++ni)
            bcol[ni] = bias[(size_t)tt * NDIM + col0 + wn + ni * 16 + l15];

        #pragma unroll
        for (int mi = 0; mi < 4; ++mi) {
            #pragma unroll
            for (int r = 0; r < 4; ++r) {
                const int grow = row0 + wm + mi * 16 + quad * 4 + r;
                if (tv[grow] == tt) {
                    float* orow = out + (size_t)grow * NDIM;
                    #pragma unroll
                    for (int ni = 0; ni < 4; ++ni) {
                        const int gcol = col0 + wn + ni * 16 + l15;
                        orow[gcol] = acc[mi][ni][r] + bcol[ni];
                    }
                }
            }
        }
    }
}

// Fallback (workspace too small for xb): round-0 proven kernel.
__global__ __launch_bounds__(256, 2)
void hetero_gemm_fallback(const float* __restrict__ x,
                          const int* __restrict__ tv,
                          const unsigned short* __restrict__ wt,
                          const float* __restrict__ bias,
                          float* __restrict__ out) {
    __shared__ uint4v ldsA[4 * 128];
    __shared__ uint4v ldsB[4 * 128];

    const int b = blockIdx.x;
    const int rowTile = ((b >> 5) << 3) | (b & 7);
    const int colTile = (b >> 3) & 3;
    const int row0 = rowTile << 7;
    const int col0 = colTile << 7;

    const int tid  = threadIdx.x;
    const int lane = tid & 63;
    const int wave = tid >> 6;
    const int wm   = (wave & 1) << 6;
    const int wn   = (wave >> 1) << 6;
    const int l15  = lane & 15;
    const int quad = lane >> 4;

    const int ra = tid >> 1;
    const int khalf = tid & 1;
    const int rtypeA = tv[row0 + ra];

    const int nb = tid & 127;
    const int g2 = tid >> 7;

    const int t0 = tv[row0];
    const int t1 = tv[row0 + 127];

    float4v acc[4][4];
    float4v zero = {0.f, 0.f, 0.f, 0.f};
    #pragma unroll
    for (int i = 0; i < 4; ++i)
        #pragma unroll
        for (int j = 0; j < 4; ++j)
            acc[i][j] = zero;

    for (int tt = t0; tt <= t1; ++tt) {
        const unsigned maskA = (rtypeA == tt) ? 0xFFFFFFFFu : 0u;
        const float* ap = x + (size_t)(row0 + ra) * KDIM + khalf * 16;
        const unsigned short* wb = wt + ((size_t)tt << 18) + (size_t)(col0 + nb) * KDIM;

        float4v av[4];
        uint4v  bv[2];
        #pragma unroll
        for (int i = 0; i < 4; ++i) av[i] = *(const float4v*)(ap + i * 4);
        bv[0] = *(const uint4v*)(wb + g2 * 8);
        bv[1] = *(const uint4v*)(wb + (g2 + 2) * 8);

        for (int kc = 0; kc < KDIM; kc += 32) {
            __syncthreads();
            uint4v pa0, pa1;
            pa0.x = pack_trunc(av[0].x, av[0].y) & maskA;
            pa0.y = pack_trunc(av[0].z, av[0].w) & maskA;
            pa0.z = pack_trunc(av[1].x, av[1].y) & maskA;
            pa0.w = pack_trunc(av[1].z, av[1].w) & maskA;
            pa1.x = pack_trunc(av[2].x, av[2].y) & maskA;
            pa1.y = pack_trunc(av[2].z, av[2].w) & maskA;
            pa1.z = pack_trunc(av[3].x, av[3].y) & maskA;
            pa1.w = pack_trunc(av[3].z, av[3].w) & maskA;
            ldsA[(khalf * 2 + 0) * 128 + ra] = pa0;
            ldsA[(khalf * 2 + 1) * 128 + ra] = pa1;
            ldsB[(g2    ) * 128 + nb] = bv[0];
            ldsB[(g2 + 2) * 128 + nb] = bv[1];
            __syncthreads();

            if (kc + 32 < KDIM) {
                const float* ap2 = ap + kc + 32;
                #pragma unroll
                for (int i = 0; i < 4; ++i) av[i] = *(const float4v*)(ap2 + i * 4);
                const unsigned short* wb2 = wb + kc + 32;
                bv[0] = *(const uint4v*)(wb2 + g2 * 8);
                bv[1] = *(const uint4v*)(wb2 + (g2 + 2) * 8);
            }

            short8 af[4], bf[4];
            #pragma unroll
            for (int mi = 0; mi < 4; ++mi)
                af[mi] = *(const short8*)&ldsA[quad * 128 + wm + mi * 16 + l15];
            #pragma unroll
            for (int ni = 0; ni < 4; ++ni)
                bf[ni] = *(const short8*)&ldsB[quad * 128 + wn + ni * 16 + l15];
            #pragma unroll
            for (int mi = 0; mi < 4; ++mi)
                #pragma unroll
                for (int ni = 0; ni < 4; ++ni)
                    acc[mi][ni] = __builtin_amdgcn_mfma_f32_16x16x32_bf16(
                        af[mi], bf[ni], acc[mi][ni], 0, 0, 0);
        }
    }

    #pragma unroll
    for (int mi = 0; mi < 4; ++mi) {
        #pragma unroll
        for (int r = 0; r < 4; ++r) {
            const int grow = row0 + wm + mi * 16 + quad * 4 + r;
            const int rt = tv[grow];
            const float* brow = bias + (size_t)rt * NDIM;
            float* orow = out + (size_t)grow * NDIM;
            #pragma unroll
            for (int ni = 0; ni < 4; ++ni) {
                const int gcol = col0 + wn + ni * 16 + l15;
                orow[gcol] = acc[mi][ni][r] + brow[gcol];
            }
        }
    }
}

extern "C" void kernel_launch(void* const* d_in, const int* in_sizes, int n_in,
                              void* d_out, int out_size, void* d_ws, size_t ws_size,
                              hipStream_t stream) {
    const float* x    = (const float*)d_in[0];
    const int*   tv   = (const int*)d_in[1];
    const float* w    = (const float*)d_in[2];
    const float* bias = (const float*)d_in[3];
    float* out = (float*)d_out;

    unsigned short* wtr = (unsigned short*)d_ws;                 // 4 MiB
    const size_t WTN  = (size_t)8 * 512 * 512;                   // wtr elems
    const size_t NEED = WTN * 2 + (size_t)NROWS * KDIM * 2;      // 132 MiB

    if (ws_size >= NEED) {
        unsigned short* xb = wtr + WTN;                          // 128 MiB
        prep_kernel<<<2560, 256, 0, stream>>>(w, wtr, x, xb);
        hetero_gemm_pre<<<4096, 256, 0, stream>>>(xb, tv, wtr, bias, out);
    } else {
        // fallback: transform W only, then round-0 proven GEMM
        prep_kernel<<<512, 256, 0, stream>>>(w, wtr, x, nullptr);
        hetero_gemm_fallback<<<4096, 256, 0, stream>>>(x, tv, wtr, bias, out);
    }
}